// Round 5
// baseline (192.788 us; speedup 1.0000x reference)
//
#include <hip/hip_runtime.h>
#include <hip/hip_cooperative_groups.h>
#include <math.h>

namespace cg = cooperative_groups;

#define BATCH 16
#define SEQ   720
#define ENC   321
#define NORD  64
#define PRED  720

// ---- ws layout (float offsets) ----
#define WS_KT    0                         // 720x64: Kt[t][m] = (A^(719-t) B)[m]
#define WS_EWT   (WS_KT + PRED*NORD)       // 64x720: EW^T [m][t']
#define WS_EVB   (WS_EWT + NORD*PRED)      // 720
#define WS_A16   (WS_EVB + PRED)           // 64x64 row-major
#define WS_A64   (WS_A16 + 4096)           // 64x64 row-major
#define WS_KSUMP (WS_A64 + 4096)           // 81x64: 64 chains64 + 16 mid + 1 head
#define WS_G     (WS_KSUMP + 81*64)        // 4 tsp x 96 x 4096, m-major [m][el]
#define WS_PSUM  (WS_G + 4*96*4096)
#define WS_PSS   (WS_PSUM + 4*16*6*64)

// R12: 4-accumulator MV body — cuts the 64-FMA dependent chain to a 4-wide tree.
#define MV4(AR, SVP, OUTV) do {                                                   \
    float _a0=0.f,_a1=0.f,_a2=0.f,_a3=0.f;                                        \
    _Pragma("unroll")                                                             \
    for (int _k = 0; _k < 4; _k++) {                                              \
        float4 _v0 = *(const float4*)&(SVP)[16*_k];                               \
        float4 _v1 = *(const float4*)&(SVP)[16*_k+4];                             \
        float4 _v2 = *(const float4*)&(SVP)[16*_k+8];                             \
        float4 _v3 = *(const float4*)&(SVP)[16*_k+12];                            \
        _a0 += (AR)[16*_k+0]*_v0.x + (AR)[16*_k+1]*_v0.y                          \
             + (AR)[16*_k+2]*_v0.z + (AR)[16*_k+3]*_v0.w;                         \
        _a1 += (AR)[16*_k+4]*_v1.x + (AR)[16*_k+5]*_v1.y                          \
             + (AR)[16*_k+6]*_v1.z + (AR)[16*_k+7]*_v1.w;                         \
        _a2 += (AR)[16*_k+8]*_v2.x + (AR)[16*_k+9]*_v2.y                          \
             + (AR)[16*_k+10]*_v2.z + (AR)[16*_k+11]*_v2.w;                       \
        _a3 += (AR)[16*_k+12]*_v3.x + (AR)[16*_k+13]*_v3.y                        \
             + (AR)[16*_k+14]*_v3.z + (AR)[16*_k+15]*_v3.w;                       \
    }                                                                             \
    OUTV = (_a0+_a1)+(_a2+_a3);                                                   \
} while (0)

#define LOADROW(AR, SRC) do {                                                     \
    _Pragma("unroll")                                                             \
    for (int _k = 0; _k < 16; _k++) {                                             \
        float4 _v = *(const float4*)&(SRC)[lane*64 + 4*_k];                       \
        (AR)[4*_k]=_v.x; (AR)[4*_k+1]=_v.y; (AR)[4*_k+2]=_v.z; (AR)[4*_k+3]=_v.w; \
    }                                                                             \
} while (0)

// ============ head phase 1: A^16 cols (blk 0-15) | K rows 0-15 (blk 16) |
// EW^T + evb (blk 17-28, input-only -> overlapped with serial chains) ============
__device__ __forceinline__ void head_phase1(const float* __restrict__ A,
        const float* __restrict__ Bv, const float* __restrict__ evalm,
        const float* __restrict__ W, const float* __restrict__ bm,
        float* __restrict__ ws, float* dsm)
{
    const int tid  = threadIdx.x;
    const int lane = tid & 63;
    const int wv   = tid >> 6;
    const int bid  = blockIdx.x;
    if (bid < 16) {
        float ar[64];
        LOADROW(ar, A);
        const int j = bid*4 + wv;            // column 0..63
        float* sv = dsm + wv*64;
        sv[lane] = (lane == j) ? 1.f : 0.f;
        for (int s = 0; s < 16; s++) {       // v <- A v, 16 times
            float nv;
            MV4(ar, sv, nv);
            sv[lane] = nv;                   // same-wave DS ordering
        }
        ws[WS_A16 + lane*64 + j] = sv[lane];
    } else if (bid == 16) {
        if (tid < 64) {
            float ar[64];
            LOADROW(ar, A);
            float* Kt = ws + WS_KT;
            float bv = Bv[lane];
            float* sv = dsm;
            sv[lane] = bv;
            Kt[(size_t)719*64 + lane] = bv;
            float ksml = bv;
            for (int j = 1; j <= 15; j++) {
                float nv;
                MV4(ar, sv, nv);
                sv[lane] = nv;
                Kt[(size_t)(719 - j)*64 + lane] = nv;
                ksml += nv;
            }
            ws[WS_KSUMP + 80*64 + lane] = ksml;
        }
    } else {
        // ---- EW^T = (eval@W)^T + evb, r = bid-17 in 0..11 ----
        float* Et = dsm;             // [m][row] pad 61
        const int r = bid - 17;
        float wcol[64];              // W[:, lane] in registers (row-invariant)
        #pragma unroll
        for (int n = 0; n < 64; n++) wcol[n] = W[n*64 + lane];
        float bv = bm[lane];
        #pragma unroll
        for (int k = 0; k < 15; k++) {
            int row = wv + k*4;              // rows 0..59
            int tp = r*60 + row;
            const float* ev = evalm + (size_t)tp*64;
            float a0=0.f,a1=0.f,a2=0.f,a3=0.f;
            #pragma unroll
            for (int kk = 0; kk < 4; kk++) {
                float4 e0_ = *(const float4*)&ev[16*kk];
                float4 e1_ = *(const float4*)&ev[16*kk+4];
                float4 e2_ = *(const float4*)&ev[16*kk+8];
                float4 e3_ = *(const float4*)&ev[16*kk+12];
                a0 += e0_.x*wcol[16*kk+0] + e0_.y*wcol[16*kk+1]
                    + e0_.z*wcol[16*kk+2] + e0_.w*wcol[16*kk+3];
                a1 += e1_.x*wcol[16*kk+4] + e1_.y*wcol[16*kk+5]
                    + e1_.z*wcol[16*kk+6] + e1_.w*wcol[16*kk+7];
                a2 += e2_.x*wcol[16*kk+8] + e2_.y*wcol[16*kk+9]
                    + e2_.z*wcol[16*kk+10] + e2_.w*wcol[16*kk+11];
                a3 += e3_.x*wcol[16*kk+12] + e3_.y*wcol[16*kk+13]
                    + e3_.z*wcol[16*kk+14] + e3_.w*wcol[16*kk+15];
            }
            Et[lane*61 + row] = (a0+a1)+(a2+a3);
            float pv = ev[lane] * bv;
            #pragma unroll
            for (int o = 32; o > 0; o >>= 1) pv += __shfl_down(pv, o);
            if (lane == 0) ws[WS_EVB + tp] = pv;
        }
        __syncthreads();
        for (int idx = tid; idx < 4096; idx += 256) {
            int m = idx >> 6, row = idx & 63;
            if (row < 60)
                ws[WS_EWT + (size_t)m*720 + r*60 + row] = Et[m*61 + row];
        }
    }
}

// ============ head phase 2: A^64 cols (blk 0-15, 4 MVs of A^16) |
// K rows 16..63 (blk 16-19: 16 chains x 3 MVs) ============
__device__ __forceinline__ void head_phase2(float* __restrict__ ws, float* dsm)
{
    const int tid  = threadIdx.x;
    const int lane = tid & 63;
    const int wv   = tid >> 6;
    const int bid  = blockIdx.x;
    if (bid < 16) {
        const float* A16 = ws + WS_A16;
        float ar[64];
        LOADROW(ar, A16);
        const int j = bid*4 + wv;
        float* sv = dsm + wv*64;
        sv[lane] = (lane == j) ? 1.f : 0.f;
        #pragma unroll
        for (int s = 0; s < 4; s++) {        // (A^16)^4 = A^64
            float nv;
            MV4(ar, sv, nv);
            sv[lane] = nv;
        }
        ws[WS_A64 + lane*64 + j] = sv[lane];
    } else if (bid < 20) {
        const float* A16 = ws + WS_A16;
        float ar[64];
        LOADROW(ar, A16);
        const int r = (bid - 16)*4 + wv;     // 0..15
        float* Kt = ws + WS_KT;
        float* sv = dsm + wv*64;
        sv[lane] = Kt[(size_t)(719 - r)*64 + lane];
        float ksml = 0.f;
        #pragma unroll
        for (int s = 1; s <= 3; s++) {       // rows r+16, r+32, r+48
            float nv;
            MV4(ar, sv, nv);
            sv[lane] = nv;
            Kt[(size_t)(719 - (r + 16*s))*64 + lane] = nv;
            ksml += nv;
        }
        ws[WS_KSUMP + (64 + r)*64 + lane] = ksml;
    }
}

// ============ head phase 3: 64 stride-64 chains, <=11 serial MVs (blk 0-15 x 4 waves) ============
__device__ __forceinline__ void head_phase3(float* __restrict__ ws, float* dsm)
{
    const int tid  = threadIdx.x;
    const int lane = tid & 63;
    const int wv   = tid >> 6;
    const int bid  = blockIdx.x;
    if (bid < 16) {
        const float* A64 = ws + WS_A64;
        float ar[64];
        LOADROW(ar, A64);
        const int r = bid*4 + wv;            // chain 0..63
        float* Kt = ws + WS_KT;
        float* sv = dsm + wv*64;
        sv[lane] = Kt[(size_t)(719 - r)*64 + lane];
        float ksml = 0.f;
        for (int j = r + 64; j <= 719; j += 64) {   // 10 or 11 steps
            float nv;
            MV4(ar, sv, nv);
            sv[lane] = nv;
            Kt[(size_t)(719 - j)*64 + lane] = nv;
            ksml += nv;
        }
        ws[WS_KSUMP + r*64 + lane] = ksml;
    }
}

__global__ __launch_bounds__(256, 1) void head_coop(const float* __restrict__ A,
        const float* __restrict__ Bv, const float* __restrict__ evalm,
        const float* __restrict__ W, const float* __restrict__ bm,
        float* __restrict__ ws)
{
    __shared__ float dsm[64*61];
    cg::grid_group g = cg::this_grid();
    head_phase1(A, Bv, evalm, W, bm, ws, dsm);
    g.sync();
    head_phase2(ws, dsm);
    g.sync();
    head_phase3(ws, dsm);
}

// fallback (non-cooperative) phase kernels
__global__ __launch_bounds__(256, 1) void head_p1(const float* __restrict__ A,
        const float* __restrict__ Bv, const float* __restrict__ evalm,
        const float* __restrict__ W, const float* __restrict__ bm,
        float* __restrict__ ws)
{ __shared__ float dsm[64*61]; head_phase1(A, Bv, evalm, W, bm, ws, dsm); }
__global__ __launch_bounds__(256, 1) void head_p2(float* __restrict__ ws)
{ __shared__ float dsm[64*61]; head_phase2(ws, dsm); }
__global__ __launch_bounds__(256, 1) void head_p3(float* __restrict__ ws)
{ __shared__ float dsm[64*61]; head_phase3(ws, dsm); }

// ============ k2: R14/R12 proven version — LDS double-buffered, acc[8][4]
// on 2 compute waves, staging waves overlap. 4 slabs of 180. ============
__device__ inline float4 ldx(const float* __restrict__ x, int b, int t, int e4)
{
    float4 r = make_float4(0.f,0.f,0.f,0.f);
    const float* p = x + ((size_t)b*SEQ + t)*ENC;
    if (e4 + 3 < ENC) r = *(const float4*)&p[e4];
    else {
        if (e4   < ENC) r.x = p[e4];
        if (e4+1 < ENC) r.y = p[e4+1];
        if (e4+2 < ENC) r.z = p[e4+2];
    }
    return r;
}

__global__ __launch_bounds__(256) void k2(const float* __restrict__ x,
        float* __restrict__ ws)
{
    __shared__ float xt[2][12*64];
    __shared__ float ks[2][12*64];
    __shared__ float redn[12*64];
    __shared__ float reds[12*64];
    const int tid = threadIdx.x;
    const int bid = blockIdx.x;
    const int b = bid / 24, rem = bid % 24;
    const int et = rem / 4, tsp = rem % 4;
    const int e0 = et*64, t0 = tsp*180;

    const bool xon = tid < 192;
    const bool kon = tid >= 64;
    const int sx_t  = tid >> 4;
    const int sx_e4 = (tid & 15) * 4;
    const int sk    = tid - 64;
    const int sk_t  = sk >> 4;
    const int sk_m4 = (sk & 15) * 4;

    const float* Kt = ws + WS_KT;
    float s0=0,s1=0,s2=0,s3=0, q0=0,q1=0,q2=0,q3=0;
    float4 rx = make_float4(0,0,0,0), rk = make_float4(0,0,0,0);

    if (xon) rx = ldx(x, b, t0 + sx_t, e0 + sx_e4);
    if (kon) rk = *(const float4*)&Kt[(size_t)(t0 + sk_t)*64 + sk_m4];
    if (xon) {
        *(float4*)&xt[0][sx_t*64 + sx_e4] = rx;
        s0+=rx.x; s1+=rx.y; s2+=rx.z; s3+=rx.w;
        q0+=rx.x*rx.x; q1+=rx.y*rx.y; q2+=rx.z*rx.z; q3+=rx.w*rx.w;
    }
    if (kon) *(float4*)&ks[0][sk_t*64 + sk_m4] = rk;

    // compute role: waves 0,1 only. el = elg*8 (+0..7), m = mgr*4 (+0..3)
    const bool con = tid < 128;
    const int elg = tid & 7;
    const int mgr = tid >> 3;       // 0..15 for con threads
    float acc[8][4];
    #pragma unroll
    for (int j = 0; j < 8; j++)
        #pragma unroll
        for (int i = 0; i < 4; i++) acc[j][i] = 0.f;

    for (int ch = 0; ch < 15; ch++) {
        if (ch + 1 < 15) {
            if (xon) rx = ldx(x, b, t0 + (ch+1)*12 + sx_t, e0 + sx_e4);
            if (kon) rk = *(const float4*)&Kt[(size_t)(t0 + (ch+1)*12 + sk_t)*64 + sk_m4];
        }
        __syncthreads();
        const float* xb = xt[ch & 1];
        const float* kb = ks[ch & 1];
        if (con) {
            #pragma unroll
            for (int tt = 0; tt < 12; tt++) {
                float4 fa = *(const float4*)&xb[tt*64 + elg*8];
                float4 fb = *(const float4*)&xb[tt*64 + elg*8 + 4];
                float4 kv = *(const float4*)&kb[tt*64 + mgr*4];
                acc[0][0]+=fa.x*kv.x; acc[0][1]+=fa.x*kv.y; acc[0][2]+=fa.x*kv.z; acc[0][3]+=fa.x*kv.w;
                acc[1][0]+=fa.y*kv.x; acc[1][1]+=fa.y*kv.y; acc[1][2]+=fa.y*kv.z; acc[1][3]+=fa.y*kv.w;
                acc[2][0]+=fa.z*kv.x; acc[2][1]+=fa.z*kv.y; acc[2][2]+=fa.z*kv.z; acc[2][3]+=fa.z*kv.w;
                acc[3][0]+=fa.w*kv.x; acc[3][1]+=fa.w*kv.y; acc[3][2]+=fa.w*kv.z; acc[3][3]+=fa.w*kv.w;
                acc[4][0]+=fb.x*kv.x; acc[4][1]+=fb.x*kv.y; acc[4][2]+=fb.x*kv.z; acc[4][3]+=fb.x*kv.w;
                acc[5][0]+=fb.y*kv.x; acc[5][1]+=fb.y*kv.y; acc[5][2]+=fb.y*kv.z; acc[5][3]+=fb.y*kv.w;
                acc[6][0]+=fb.z*kv.x; acc[6][1]+=fb.z*kv.y; acc[6][2]+=fb.z*kv.z; acc[6][3]+=fb.z*kv.w;
                acc[7][0]+=fb.w*kv.x; acc[7][1]+=fb.w*kv.y; acc[7][2]+=fb.w*kv.z; acc[7][3]+=fb.w*kv.w;
            }
        }
        if (ch + 1 < 15) {
            if (xon) {
                *(float4*)&xt[(ch+1)&1][sx_t*64 + sx_e4] = rx;
                s0+=rx.x; s1+=rx.y; s2+=rx.z; s3+=rx.w;
                q0+=rx.x*rx.x; q1+=rx.y*rx.y; q2+=rx.z*rx.z; q3+=rx.w*rx.w;
            }
            if (kon) *(float4*)&ks[(ch+1)&1][sk_t*64 + sk_m4] = rk;
        }
    }

    if (con) {
        float* g = ws + WS_G + (size_t)(tsp*96 + b*6 + et)*4096;
        #pragma unroll
        for (int i = 0; i < 4; i++) {
            float* gr = g + (mgr*4 + i)*64 + elg*8;
            *(float4*)&gr[0] = make_float4(acc[0][i], acc[1][i], acc[2][i], acc[3][i]);
            *(float4*)&gr[4] = make_float4(acc[4][i], acc[5][i], acc[6][i], acc[7][i]);
        }
    }

    __syncthreads();
    if (xon) {
        redn[sx_t*64 + sx_e4+0] = s0; redn[sx_t*64 + sx_e4+1] = s1;
        redn[sx_t*64 + sx_e4+2] = s2; redn[sx_t*64 + sx_e4+3] = s3;
        reds[sx_t*64 + sx_e4+0] = q0; reds[sx_t*64 + sx_e4+1] = q1;
        reds[sx_t*64 + sx_e4+2] = q2; reds[sx_t*64 + sx_e4+3] = q3;
    }
    __syncthreads();
    if (tid < 64) {
        float s = 0.f, q = 0.f;
        #pragma unroll
        for (int rr = 0; rr < 12; rr++) { s += redn[rr*64 + tid]; q += reds[rr*64 + tid]; }
        const size_t o = (size_t)((tsp*16 + b)*6 + et)*64 + tid;
        ws[WS_PSUM + o] = s;
        ws[WS_PSS  + o] = q;
    }
}

// ============ k3f: R14 one-pass m-loop (4 G slabs), 81 ksum partials ============
#define K3ROW(r, wvv) \
    acc[r][0]+=(wvv)*c0.x; acc[r][1]+=(wvv)*c0.y; acc[r][2]+=(wvv)*c0.z; acc[r][3]+=(wvv)*c0.w; \
    acc[r][4]+=(wvv)*c1.x; acc[r][5]+=(wvv)*c1.y; acc[r][6]+=(wvv)*c1.z; acc[r][7]+=(wvv)*c1.w;

__global__ __launch_bounds__(256) void k3f(const float* __restrict__ aw,
        const float* __restrict__ ab, const float* __restrict__ ws,
        float* __restrict__ out)
{
    __shared__ float Cm[64*192];     // [m][g*12 + j], el = g*8 + j  (49 KB)
    __shared__ float EWm[64*196];    // [m][t' 192], stride 196      (50 KB)
    __shared__ float ssc[128], ssh[128], sP[128], sQ[128];
    __shared__ float kss[64];
    const int tid = threadIdx.x;
    const int b   = blockIdx.x / 12;
    const int rr  = blockIdx.x % 12;
    const int eT  = rr >> 2;
    const int tq  = rr & 3;
    const int e0  = eT * 128;
    const int et0 = eT * 2;

    if (tid < 128) {
        const int el = tid, e = e0 + el;
        const int et = et0 + (el >> 6), eli = el & 63;
        float s = 0.f, q = 0.f;
        #pragma unroll
        for (int tsp = 0; tsp < 4; tsp++) {
            const size_t o = (size_t)((tsp*16 + b)*6 + et)*64 + eli;
            s += ws[WS_PSUM + o];
            q += ws[WS_PSS  + o];
        }
        float mean = s * (1.0f/SEQ);
        float var  = q * (1.0f/SEQ) - mean*mean;
        float sd   = sqrtf(var + 1e-5f);
        if (e < ENC) {
            float a = aw[e], av = ab[e];
            float sc = a / sd;
            float P  = sd / (a + 1e-10f);
            ssc[el] = sc; ssh[el] = av - mean*sc;
            sP[el]  = P;  sQ[el]  = mean - av*P;
        } else {
            ssc[el]=0.f; ssh[el]=0.f; sP[el]=0.f; sQ[el]=0.f;
        }
    }
    if (tid < 64) {
        float s = 0.f;
        for (int p = 0; p < 81; p++) s += ws[WS_KSUMP + p*64 + tid];
        kss[tid] = s;
    }
    __syncthreads();

    // ---- G (4 slabs) -> Cm, padded layout ----
    const float* G = ws + WS_G;
    #pragma unroll
    for (int k = 0; k < 8; k++) {
        int slot = k*256 + tid;
        int m = slot >> 5, el4 = (slot & 31) * 4;
        int et = et0 + (el4 >> 6), eli4 = el4 & 63;
        size_t base = (size_t)(b*6 + et)*4096 + m*64 + eli4;
        float4 g0 = *(const float4*)&G[base];
        float4 g1 = *(const float4*)&G[base + (size_t) 96*4096];
        float4 g2 = *(const float4*)&G[base + (size_t)192*4096];
        float4 g3 = *(const float4*)&G[base + (size_t)288*4096];
        float km = kss[m];
        float4 sc = *(const float4*)&ssc[el4];
        float4 sh = *(const float4*)&ssh[el4];
        float4 c;
        c.x = sc.x*(g0.x+g1.x+g2.x+g3.x) + sh.x*km;
        c.y = sc.y*(g0.y+g1.y+g2.y+g3.y) + sh.y*km;
        c.z = sc.z*(g0.z+g1.z+g2.z+g3.z) + sh.z*km;
        c.w = sc.w*(g0.w+g1.w+g2.w+g3.w) + sh.w*km;
        *(float4*)&Cm[m*192 + (el4>>3)*12 + (el4&7)] = c;
    }

    // ---- EWT -> EWm [m][t' 192] ----
    const float* EWT = ws + WS_EWT;
    #pragma unroll
    for (int it = 0; it < 12; it++) {
        int slot = it*256 + tid;
        int m = slot / 48, t4 = (slot % 48) * 4;
        int tp = tq*192 + t4;
        float4 v;
        if (tp + 3 < PRED) v = *(const float4*)&EWT[(size_t)m*720 + tp];
        else {
            v = make_float4(0.f,0.f,0.f,0.f);
            if (tp   < PRED) v.x = EWT[(size_t)m*720 + tp];
            if (tp+1 < PRED) v.y = EWT[(size_t)m*720 + tp+1];
            if (tp+2 < PRED) v.z = EWT[(size_t)m*720 + tp+2];
        }
        *(float4*)&EWm[m*196 + t4] = v;
    }
    __syncthreads();

    // ---- m-loop: acc[t'12][el8] ----
    const int tx = tid & 15;      // el group: el = tx*8 + j
    const int ty = tid >> 4;      // t' group: tp = tq*192 + ty*12 + r
    float acc[12][8];
    #pragma unroll
    for (int r = 0; r < 12; r++)
        #pragma unroll
        for (int j = 0; j < 8; j++) acc[r][j] = 0.f;

    const float* cb = Cm  + tx*12;
    const float* wb = EWm + ty*12;
    #pragma unroll 2
    for (int m = 0; m < 64; m++) {
        float4 c0 = *(const float4*)&cb[m*192];
        float4 c1 = *(const float4*)&cb[m*192 + 4];
        float4 w0 = *(const float4*)&wb[m*196];
        float4 w1 = *(const float4*)&wb[m*196 + 4];
        float4 w2 = *(const float4*)&wb[m*196 + 8];
        K3ROW(0,  w0.x) K3ROW(1,  w0.y) K3ROW(2,  w0.z) K3ROW(3,  w0.w)
        K3ROW(4,  w1.x) K3ROW(5,  w1.y) K3ROW(6,  w1.z) K3ROW(7,  w1.w)
        K3ROW(8,  w2.x) K3ROW(9,  w2.y) K3ROW(10, w2.z) K3ROW(11, w2.w)
    }

    // ---- epilogue ----
    const int elb = tx*8;
    const int eb  = e0 + elb;
    float4 Pa = *(const float4*)&sP[elb];
    float4 Pb = *(const float4*)&sP[elb+4];
    float4 Qa = *(const float4*)&sQ[elb];
    float4 Qb = *(const float4*)&sQ[elb+4];
    const float* evb = ws + WS_EVB;
    #pragma unroll
    for (int r = 0; r < 12; r++) {
        int tp = tq*192 + ty*12 + r;
        if (tp < PRED) {
            float ev = evb[tp];
            float* op = out + ((size_t)b*PRED + tp)*ENC;
            if (eb + 7 < ENC) {
                float4 o0, o1;
                o0.x = (acc[r][0]+ev)*Pa.x + Qa.x;
                o0.y = (acc[r][1]+ev)*Pa.y + Qa.y;
                o0.z = (acc[r][2]+ev)*Pa.z + Qa.z;
                o0.w = (acc[r][3]+ev)*Pa.w + Qa.w;
                o1.x = (acc[r][4]+ev)*Pb.x + Qb.x;
                o1.y = (acc[r][5]+ev)*Pb.y + Qb.y;
                o1.z = (acc[r][6]+ev)*Pb.z + Qb.z;
                o1.w = (acc[r][7]+ev)*Pb.w + Qb.w;
                *(float4*)&op[eb]   = o0;
                *(float4*)&op[eb+4] = o1;
            } else {
                if (eb   < ENC) op[eb  ] = (acc[r][0]+ev)*Pa.x + Qa.x;
                if (eb+1 < ENC) op[eb+1] = (acc[r][1]+ev)*Pa.y + Qa.y;
                if (eb+2 < ENC) op[eb+2] = (acc[r][2]+ev)*Pa.z + Qa.z;
                if (eb+3 < ENC) op[eb+3] = (acc[r][3]+ev)*Pa.w + Qa.w;
                if (eb+4 < ENC) op[eb+4] = (acc[r][4]+ev)*Pb.x + Qb.x;
                if (eb+5 < ENC) op[eb+5] = (acc[r][5]+ev)*Pb.y + Qb.y;
                if (eb+6 < ENC) op[eb+6] = (acc[r][6]+ev)*Pb.z + Qb.z;
                if (eb+7 < ENC) op[eb+7] = (acc[r][7]+ev)*Pb.w + Qb.w;
            }
        }
    }
}

extern "C" void kernel_launch(void* const* d_in, const int* in_sizes, int n_in,
                              void* d_out, int out_size, void* d_ws, size_t ws_size,
                              hipStream_t stream)
{
    const float* x     = (const float*)d_in[0];
    const float* A     = (const float*)d_in[1];
    const float* Bv    = (const float*)d_in[2];
    const float* evalm = (const float*)d_in[3];
    const float* W     = (const float*)d_in[4];
    const float* bm    = (const float*)d_in[5];
    const float* aw    = (const float*)d_in[6];
    const float* ab    = (const float*)d_in[7];
    float* ws  = (float*)d_ws;
    float* out = (float*)d_out;

    void* hargs[6] = {(void*)&A, (void*)&Bv, (void*)&evalm,
                      (void*)&W, (void*)&bm, (void*)&ws};
    hipError_t ce = hipLaunchCooperativeKernel((void*)head_coop, dim3(29), dim3(256),
                                               hargs, 0, stream);
    if (ce != hipSuccess) {
        // fallback: same phases as plain launches (no grid.sync inside)
        head_p1<<<29, 256, 0, stream>>>(A, Bv, evalm, W, bm, ws);
        head_p2<<<20, 256, 0, stream>>>(ws);
        head_p3<<<16, 256, 0, stream>>>(ws);
    }
    k2 <<<BATCH*6*4, 256, 0, stream>>>(x, ws);
    k3f<<<192, 256, 0, stream>>>(aw, ab, ws, out);
}

// Round 6
// 143.772 us; speedup vs baseline: 1.3409x; 1.3409x over previous
//
#include <hip/hip_runtime.h>
#include <math.h>

#define BATCH 16
#define SEQ   720
#define ENC   321
#define NORD  64
#define PRED  720
#define NPAIR (BATCH*ENC)    // 5136

// ---- ws layout (float offsets) ----
#define WS_KT    0                         // 720x64: Kt[t][m] = (A^(719-t) B)[m]
#define WS_EWT   (WS_KT + PRED*NORD)       // 64x720: EW^T [m][t']
#define WS_EVB   (WS_EWT + NORD*PRED)      // 720
#define WS_A16   (WS_EVB + PRED)           // 64x64 row-major
#define WS_KSUMP (WS_A16 + 4096)           // 17x64 Ksum partials (16 chains + 1 prep)
#define WS_G     (WS_KSUMP + 17*64)        // 4 tsp x 96 x 4096, m-major [m][el]
#define WS_PSUM  (WS_G + 4*96*4096)
#define WS_PSS   (WS_PSUM + 4*16*6*64)

// R12: 4-accumulator MV body — cuts the 64-FMA dependent chain to a 4-wide tree.
#define MV4(AR, SVP, OUTV) do {                                                   \
    float _a0=0.f,_a1=0.f,_a2=0.f,_a3=0.f;                                        \
    _Pragma("unroll")                                                             \
    for (int _k = 0; _k < 4; _k++) {                                              \
        float4 _v0 = *(const float4*)&(SVP)[16*_k];                               \
        float4 _v1 = *(const float4*)&(SVP)[16*_k+4];                             \
        float4 _v2 = *(const float4*)&(SVP)[16*_k+8];                             \
        float4 _v3 = *(const float4*)&(SVP)[16*_k+12];                            \
        _a0 += (AR)[16*_k+0]*_v0.x + (AR)[16*_k+1]*_v0.y                          \
             + (AR)[16*_k+2]*_v0.z + (AR)[16*_k+3]*_v0.w;                         \
        _a1 += (AR)[16*_k+4]*_v1.x + (AR)[16*_k+5]*_v1.y                          \
             + (AR)[16*_k+6]*_v1.z + (AR)[16*_k+7]*_v1.w;                         \
        _a2 += (AR)[16*_k+8]*_v2.x + (AR)[16*_k+9]*_v2.y                          \
             + (AR)[16*_k+10]*_v2.z + (AR)[16*_k+11]*_v2.w;                       \
        _a3 += (AR)[16*_k+12]*_v3.x + (AR)[16*_k+13]*_v3.y                        \
             + (AR)[16*_k+14]*_v3.z + (AR)[16*_k+15]*_v3.w;                       \
    }                                                                             \
    OUTV = (_a0+_a1)+(_a2+_a3);                                                   \
} while (0)

// ============ prep: A^16 as 64 depth-16 column chains; K rows 0..15 from B ============
__global__ __launch_bounds__(256, 1) void prep(const float* __restrict__ A,
        const float* __restrict__ Bv, float* __restrict__ ws)
{
    __shared__ float sv[4][64];
    const int tid  = threadIdx.x;
    const int lane = tid & 63;
    const int wv   = tid >> 6;
    if (blockIdx.x < 16) {
        float ar[64];                        // row `lane` of A
        #pragma unroll
        for (int k = 0; k < 16; k++) {
            float4 v = *(const float4*)&A[lane*64 + 4*k];
            ar[4*k]=v.x; ar[4*k+1]=v.y; ar[4*k+2]=v.z; ar[4*k+3]=v.w;
        }
        const int j = blockIdx.x*4 + wv;     // column 0..63
        sv[wv][lane] = (lane == j) ? 1.f : 0.f;
        for (int s = 0; s < 16; s++) {       // v <- A v, 16 times
            float nv;
            MV4(ar, &sv[wv][0], nv);
            sv[wv][lane] = nv;               // same-wave DS ordering
        }
        ws[WS_A16 + lane*64 + j] = sv[wv][lane];   // element (lane, j), row-major
    } else {
        // ---- K rows 0..15 (one wave): K[0]=B, K[j]=A K[j-1] ----
        if (tid >= 64) return;
        float ar[64];
        #pragma unroll
        for (int k = 0; k < 16; k++) {
            float4 v = *(const float4*)&A[lane*64 + 4*k];
            ar[4*k]=v.x; ar[4*k+1]=v.y; ar[4*k+2]=v.z; ar[4*k+3]=v.w;
        }
        float* Kt = ws + WS_KT;
        float bv = Bv[lane];
        sv[0][lane] = bv;
        Kt[(size_t)719*64 + lane] = bv;
        float ksml = bv;
        for (int j = 1; j <= 15; j++) {
            float nv;
            MV4(ar, &sv[0][0], nv);
            sv[0][lane] = nv;
            Kt[(size_t)(719 - j)*64 + lane] = nv;
            ksml += nv;
        }
        ws[WS_KSUMP + 16*64 + lane] = ksml;  // partial: rows 0..15
    }
}

// ============ chainsEW: [bid<16] chain r: 44 steps of A^16; [bid>=16] EW^T ============
__global__ __launch_bounds__(256, 1) void chainsEW(const float* __restrict__ evalm,
        const float* __restrict__ W, const float* __restrict__ bm,
        float* __restrict__ ws)
{
    __shared__ float dsm[64*61];
    const int tid  = threadIdx.x;
    const int lane = tid & 63;
    const int wv   = tid >> 6;
    if (blockIdx.x < 16) {
        if (tid >= 64) return;       // 1 wave per chain block
        float* sv = dsm;
        const int r = blockIdx.x;    // chain 0..15
        const float* A16 = ws + WS_A16;
        float* Kt = ws + WS_KT;
        float ar16[64];
        #pragma unroll
        for (int k = 0; k < 16; k++) {
            float4 v = *(const float4*)&A16[lane*64 + 4*k];
            ar16[4*k]=v.x; ar16[4*k+1]=v.y; ar16[4*k+2]=v.z; ar16[4*k+3]=v.w;
        }
        float ksml = 0.f;
        sv[lane] = Kt[(size_t)(719 - r)*64 + lane];   // seed K[r]
        for (int j = r + 16; j <= 719; j += 16) {     // 44 steps
            float nv;
            MV4(ar16, sv, nv);
            sv[lane] = nv;                            // same-wave DS ordering
            Kt[(size_t)(719 - j)*64 + lane] = nv;
            ksml += nv;
        }
        ws[WS_KSUMP + r*64 + lane] = ksml;
    } else {
        float* Et = dsm;             // [m][row] pad 61
        const int r = blockIdx.x - 16;
        float wcol[64];              // W[:, lane] in registers (row-invariant)
        #pragma unroll
        for (int n = 0; n < 64; n++) wcol[n] = W[n*64 + lane];
        float bv = bm[lane];
        #pragma unroll
        for (int k = 0; k < 15; k++) {
            int row = wv + k*4;              // rows 0..59
            int tp = r*60 + row;
            const float* ev = evalm + (size_t)tp*64;
            float a0=0.f,a1=0.f,a2=0.f,a3=0.f;
            #pragma unroll
            for (int kk = 0; kk < 4; kk++) {
                float4 e0_ = *(const float4*)&ev[16*kk];
                float4 e1_ = *(const float4*)&ev[16*kk+4];
                float4 e2_ = *(const float4*)&ev[16*kk+8];
                float4 e3_ = *(const float4*)&ev[16*kk+12];
                a0 += e0_.x*wcol[16*kk+0] + e0_.y*wcol[16*kk+1]
                    + e0_.z*wcol[16*kk+2] + e0_.w*wcol[16*kk+3];
                a1 += e1_.x*wcol[16*kk+4] + e1_.y*wcol[16*kk+5]
                    + e1_.z*wcol[16*kk+6] + e1_.w*wcol[16*kk+7];
                a2 += e2_.x*wcol[16*kk+8] + e2_.y*wcol[16*kk+9]
                    + e2_.z*wcol[16*kk+10] + e2_.w*wcol[16*kk+11];
                a3 += e3_.x*wcol[16*kk+12] + e3_.y*wcol[16*kk+13]
                    + e3_.z*wcol[16*kk+14] + e3_.w*wcol[16*kk+15];
            }
            Et[lane*61 + row] = (a0+a1)+(a2+a3);
            float pv = ev[lane] * bv;
            #pragma unroll
            for (int o = 32; o > 0; o >>= 1) pv += __shfl_down(pv, o);
            if (lane == 0) ws[WS_EVB + tp] = pv;
        }
        __syncthreads();
        for (int idx = tid; idx < 4096; idx += 256) {
            int m = idx >> 6, row = idx & 63;
            if (row < 60)
                ws[WS_EWT + (size_t)m*720 + r*60 + row] = Et[m*61 + row];
        }
    }
}

// ============ k2 (R17): x staged in LDS dbuf (proven shell), K read DIRECT from
// global (16-lane broadcast, L2-resident) — deletes K staging + 1/3 of LDS reads.
// Compute spread over ALL 4 waves: per-thread el4 x m4 (acc[4][4]).
// 2-block-CU model: LDS 17.3k cyc (was 25.9k), VALU 11.5k/SIMD (was 23k). ============
__device__ inline float4 ldx(const float* __restrict__ x, int b, int t, int e4)
{
    float4 r = make_float4(0.f,0.f,0.f,0.f);
    const float* p = x + ((size_t)b*SEQ + t)*ENC;
    if (e4 + 3 < ENC) r = *(const float4*)&p[e4];
    else {
        if (e4   < ENC) r.x = p[e4];
        if (e4+1 < ENC) r.y = p[e4+1];
        if (e4+2 < ENC) r.z = p[e4+2];
    }
    return r;
}

__global__ __launch_bounds__(256) void k2(const float* __restrict__ x,
        float* __restrict__ ws)
{
    __shared__ float xt[2][12*64];
    __shared__ float redn[12*64];
    __shared__ float reds[12*64];
    const int tid = threadIdx.x;
    const int bid = blockIdx.x;
    const int b = bid / 24, rem = bid % 24;
    const int et = rem / 4, tsp = rem % 4;
    const int e0 = et*64, t0 = tsp*180;

    const bool xon = tid < 192;
    const int sx_t  = tid >> 4;          // 0..11
    const int sx_e4 = (tid & 15) * 4;

    const float* Kt = ws + WS_KT;
    float s0=0,s1=0,s2=0,s3=0, q0=0,q1=0,q2=0,q3=0;
    float4 rx = make_float4(0,0,0,0);

    if (xon) {
        rx = ldx(x, b, t0 + sx_t, e0 + sx_e4);
        *(float4*)&xt[0][sx_t*64 + sx_e4] = rx;
        s0+=rx.x; s1+=rx.y; s2+=rx.z; s3+=rx.w;
        q0+=rx.x*rx.x; q1+=rx.y*rx.y; q2+=rx.z*rx.z; q3+=rx.w*rx.w;
    }

    // compute role: all 4 waves. el = elg*4 (+0..3), m = mgr*4 (+0..3)
    const int elg = tid & 15;
    const int mgr = tid >> 4;            // 0..15
    float acc[4][4];
    #pragma unroll
    for (int j = 0; j < 4; j++)
        #pragma unroll
        for (int i = 0; i < 4; i++) acc[j][i] = 0.f;

    for (int ch = 0; ch < 15; ch++) {
        if (ch + 1 < 15 && xon)
            rx = ldx(x, b, t0 + (ch+1)*12 + sx_t, e0 + sx_e4);
        __syncthreads();
        const float* xb = xt[ch & 1];
        const float* kp = Kt + (size_t)(t0 + ch*12)*64 + mgr*4;
        #pragma unroll
        for (int tt = 0; tt < 12; tt++) {
            float4 fa = *(const float4*)&xb[tt*64 + elg*4];
            float4 kv = *(const float4*)&kp[tt*64];     // 16-lane broadcast, L2
            acc[0][0]+=fa.x*kv.x; acc[0][1]+=fa.x*kv.y; acc[0][2]+=fa.x*kv.z; acc[0][3]+=fa.x*kv.w;
            acc[1][0]+=fa.y*kv.x; acc[1][1]+=fa.y*kv.y; acc[1][2]+=fa.y*kv.z; acc[1][3]+=fa.y*kv.w;
            acc[2][0]+=fa.z*kv.x; acc[2][1]+=fa.z*kv.y; acc[2][2]+=fa.z*kv.z; acc[2][3]+=fa.z*kv.w;
            acc[3][0]+=fa.w*kv.x; acc[3][1]+=fa.w*kv.y; acc[3][2]+=fa.w*kv.z; acc[3][3]+=fa.w*kv.w;
        }
        if (ch + 1 < 15 && xon) {
            *(float4*)&xt[(ch+1)&1][sx_t*64 + sx_e4] = rx;
            s0+=rx.x; s1+=rx.y; s2+=rx.z; s3+=rx.w;
            q0+=rx.x*rx.x; q1+=rx.y*rx.y; q2+=rx.z*rx.z; q3+=rx.w*rx.w;
        }
    }

    float* g = ws + WS_G + (size_t)(tsp*96 + b*6 + et)*4096;
    #pragma unroll
    for (int i = 0; i < 4; i++)
        *(float4*)&g[(mgr*4 + i)*64 + elg*4] =
            make_float4(acc[0][i], acc[1][i], acc[2][i], acc[3][i]);

    __syncthreads();
    if (xon) {
        redn[sx_t*64 + sx_e4+0] = s0; redn[sx_t*64 + sx_e4+1] = s1;
        redn[sx_t*64 + sx_e4+2] = s2; redn[sx_t*64 + sx_e4+3] = s3;
        reds[sx_t*64 + sx_e4+0] = q0; reds[sx_t*64 + sx_e4+1] = q1;
        reds[sx_t*64 + sx_e4+2] = q2; reds[sx_t*64 + sx_e4+3] = q3;
    }
    __syncthreads();
    if (tid < 64) {
        float s = 0.f, q = 0.f;
        #pragma unroll
        for (int rr = 0; rr < 12; rr++) { s += redn[rr*64 + tid]; q += reds[rr*64 + tid]; }
        const size_t o = (size_t)((tsp*16 + b)*6 + et)*64 + tid;
        ws[WS_PSUM + o] = s;
        ws[WS_PSS  + o] = q;
    }
}

// ============ k3f (R14): one-pass m-loop (4 G slabs), 17 ksum partials ============
#define K3ROW(r, wvv) \
    acc[r][0]+=(wvv)*c0.x; acc[r][1]+=(wvv)*c0.y; acc[r][2]+=(wvv)*c0.z; acc[r][3]+=(wvv)*c0.w; \
    acc[r][4]+=(wvv)*c1.x; acc[r][5]+=(wvv)*c1.y; acc[r][6]+=(wvv)*c1.z; acc[r][7]+=(wvv)*c1.w;

__global__ __launch_bounds__(256) void k3f(const float* __restrict__ aw,
        const float* __restrict__ ab, const float* __restrict__ ws,
        float* __restrict__ out)
{
    __shared__ float Cm[64*192];     // [m][g*12 + j], el = g*8 + j  (49 KB)
    __shared__ float EWm[64*196];    // [m][t' 192], stride 196      (50 KB)
    __shared__ float ssc[128], ssh[128], sP[128], sQ[128];
    __shared__ float kss[64];
    const int tid = threadIdx.x;
    const int b   = blockIdx.x / 12;
    const int rr  = blockIdx.x % 12;
    const int eT  = rr >> 2;
    const int tq  = rr & 3;
    const int e0  = eT * 128;
    const int et0 = eT * 2;

    if (tid < 128) {
        const int el = tid, e = e0 + el;
        const int et = et0 + (el >> 6), eli = el & 63;
        float s = 0.f, q = 0.f;
        #pragma unroll
        for (int tsp = 0; tsp < 4; tsp++) {
            const size_t o = (size_t)((tsp*16 + b)*6 + et)*64 + eli;
            s += ws[WS_PSUM + o];
            q += ws[WS_PSS  + o];
        }
        float mean = s * (1.0f/SEQ);
        float var  = q * (1.0f/SEQ) - mean*mean;
        float sd   = sqrtf(var + 1e-5f);
        if (e < ENC) {
            float a = aw[e], av = ab[e];
            float sc = a / sd;
            float P  = sd / (a + 1e-10f);
            ssc[el] = sc; ssh[el] = av - mean*sc;
            sP[el]  = P;  sQ[el]  = mean - av*P;
        } else {
            ssc[el]=0.f; ssh[el]=0.f; sP[el]=0.f; sQ[el]=0.f;
        }
    }
    if (tid < 64) {
        float s = 0.f;
        #pragma unroll
        for (int p = 0; p < 17; p++) s += ws[WS_KSUMP + p*64 + tid];
        kss[tid] = s;
    }
    __syncthreads();

    // ---- G (4 slabs) -> Cm, padded layout ----
    const float* G = ws + WS_G;
    #pragma unroll
    for (int k = 0; k < 8; k++) {
        int slot = k*256 + tid;
        int m = slot >> 5, el4 = (slot & 31) * 4;
        int et = et0 + (el4 >> 6), eli4 = el4 & 63;
        size_t base = (size_t)(b*6 + et)*4096 + m*64 + eli4;
        float4 g0 = *(const float4*)&G[base];
        float4 g1 = *(const float4*)&G[base + (size_t) 96*4096];
        float4 g2 = *(const float4*)&G[base + (size_t)192*4096];
        float4 g3 = *(const float4*)&G[base + (size_t)288*4096];
        float km = kss[m];
        float4 sc = *(const float4*)&ssc[el4];
        float4 sh = *(const float4*)&ssh[el4];
        float4 c;
        c.x = sc.x*(g0.x+g1.x+g2.x+g3.x) + sh.x*km;
        c.y = sc.y*(g0.y+g1.y+g2.y+g3.y) + sh.y*km;
        c.z = sc.z*(g0.z+g1.z+g2.z+g3.z) + sh.z*km;
        c.w = sc.w*(g0.w+g1.w+g2.w+g3.w) + sh.w*km;
        *(float4*)&Cm[m*192 + (el4>>3)*12 + (el4&7)] = c;
    }

    // ---- EWT -> EWm [m][t' 192] ----
    const float* EWT = ws + WS_EWT;
    #pragma unroll
    for (int it = 0; it < 12; it++) {
        int slot = it*256 + tid;
        int m = slot / 48, t4 = (slot % 48) * 4;
        int tp = tq*192 + t4;
        float4 v;
        if (tp + 3 < PRED) v = *(const float4*)&EWT[(size_t)m*720 + tp];
        else {
            v = make_float4(0.f,0.f,0.f,0.f);
            if (tp   < PRED) v.x = EWT[(size_t)m*720 + tp];
            if (tp+1 < PRED) v.y = EWT[(size_t)m*720 + tp+1];
            if (tp+2 < PRED) v.z = EWT[(size_t)m*720 + tp+2];
        }
        *(float4*)&EWm[m*196 + t4] = v;
    }
    __syncthreads();

    // ---- m-loop: acc[t'12][el8] ----
    const int tx = tid & 15;      // el group: el = tx*8 + j
    const int ty = tid >> 4;      // t' group: tp = tq*192 + ty*12 + r
    float acc[12][8];
    #pragma unroll
    for (int r = 0; r < 12; r++)
        #pragma unroll
        for (int j = 0; j < 8; j++) acc[r][j] = 0.f;

    const float* cb = Cm  + tx*12;
    const float* wb = EWm + ty*12;
    #pragma unroll 2
    for (int m = 0; m < 64; m++) {
        float4 c0 = *(const float4*)&cb[m*192];
        float4 c1 = *(const float4*)&cb[m*192 + 4];
        float4 w0 = *(const float4*)&wb[m*196];
        float4 w1 = *(const float4*)&wb[m*196 + 4];
        float4 w2 = *(const float4*)&wb[m*196 + 8];
        K3ROW(0,  w0.x) K3ROW(1,  w0.y) K3ROW(2,  w0.z) K3ROW(3,  w0.w)
        K3ROW(4,  w1.x) K3ROW(5,  w1.y) K3ROW(6,  w1.z) K3ROW(7,  w1.w)
        K3ROW(8,  w2.x) K3ROW(9,  w2.y) K3ROW(10, w2.z) K3ROW(11, w2.w)
    }

    // ---- epilogue ----
    const int elb = tx*8;
    const int eb  = e0 + elb;
    float4 Pa = *(const float4*)&sP[elb];
    float4 Pb = *(const float4*)&sP[elb+4];
    float4 Qa = *(const float4*)&sQ[elb];
    float4 Qb = *(const float4*)&sQ[elb+4];
    const float* evb = ws + WS_EVB;
    #pragma unroll
    for (int r = 0; r < 12; r++) {
        int tp = tq*192 + ty*12 + r;
        if (tp < PRED) {
            float ev = evb[tp];
            float* op = out + ((size_t)b*PRED + tp)*ENC;
            if (eb + 7 < ENC) {
                float4 o0, o1;
                o0.x = (acc[r][0]+ev)*Pa.x + Qa.x;
                o0.y = (acc[r][1]+ev)*Pa.y + Qa.y;
                o0.z = (acc[r][2]+ev)*Pa.z + Qa.z;
                o0.w = (acc[r][3]+ev)*Pa.w + Qa.w;
                o1.x = (acc[r][4]+ev)*Pb.x + Qb.x;
                o1.y = (acc[r][5]+ev)*Pb.y + Qb.y;
                o1.z = (acc[r][6]+ev)*Pb.z + Qb.z;
                o1.w = (acc[r][7]+ev)*Pb.w + Qb.w;
                *(float4*)&op[eb]   = o0;
                *(float4*)&op[eb+4] = o1;
            } else {
                if (eb   < ENC) op[eb  ] = (acc[r][0]+ev)*Pa.x + Qa.x;
                if (eb+1 < ENC) op[eb+1] = (acc[r][1]+ev)*Pa.y + Qa.y;
                if (eb+2 < ENC) op[eb+2] = (acc[r][2]+ev)*Pa.z + Qa.z;
                if (eb+3 < ENC) op[eb+3] = (acc[r][3]+ev)*Pa.w + Qa.w;
                if (eb+4 < ENC) op[eb+4] = (acc[r][4]+ev)*Pb.x + Qb.x;
                if (eb+5 < ENC) op[eb+5] = (acc[r][5]+ev)*Pb.y + Qb.y;
                if (eb+6 < ENC) op[eb+6] = (acc[r][6]+ev)*Pb.z + Qb.z;
                if (eb+7 < ENC) op[eb+7] = (acc[r][7]+ev)*Pb.w + Qb.w;
            }
        }
    }
}

extern "C" void kernel_launch(void* const* d_in, const int* in_sizes, int n_in,
                              void* d_out, int out_size, void* d_ws, size_t ws_size,
                              hipStream_t stream)
{
    const float* x     = (const float*)d_in[0];
    const float* A     = (const float*)d_in[1];
    const float* Bv    = (const float*)d_in[2];
    const float* evalm = (const float*)d_in[3];
    const float* W     = (const float*)d_in[4];
    const float* bm    = (const float*)d_in[5];
    const float* aw    = (const float*)d_in[6];
    const float* ab    = (const float*)d_in[7];
    float* ws  = (float*)d_ws;
    float* out = (float*)d_out;

    prep    <<<17, 256, 0, stream>>>(A, Bv, ws);
    chainsEW<<<28, 256, 0, stream>>>(evalm, W, bm, ws);
    k2      <<<BATCH*6*4, 256, 0, stream>>>(x, ws);
    k3f     <<<192, 256, 0, stream>>>(aw, ab, ws, out);
}